// Round 1
// baseline (705.849 us; speedup 1.0000x reference)
//
#include <hip/hip_runtime.h>
#include <stdint.h>

typedef unsigned short u16;
typedef __bf16 bf16x8 __attribute__((ext_vector_type(8)));
typedef float f32x4 __attribute__((ext_vector_type(4)));

// Geometry
// x: [8, 512, 100, 100] NCHW (dtype runtime-detected: f32 or bf16). Padded grid 102x102.
// xt: channels-last padded input [b][row][c] bf16, row = 128-guard + p, per-batch stride 10752 rows.
// feat: [b][p][o] bf16, per-batch stride 10496 rows.
// wA: [o][cchunk*576 + s*64 + c_in]  (K-order: c-chunk major, shift s, 64 c_in)
#define XT_STRIDE 10752
#define XT_GUARD  128
#define NPAD      10496

__device__ __forceinline__ float b2f(u16 u) {
  union { unsigned int i; float f; } v; v.i = ((unsigned int)u) << 16; return v.f;
}
__device__ __forceinline__ u16 f2b(float f) {
  union { float f; unsigned int i; } v; v.f = f;
  unsigned int u = v.i;
  unsigned int r = u + 0x7FFFu + ((u >> 16) & 1u);  // RNE, finite inputs
  return (u16)(r >> 16);
}
__device__ __forceinline__ float ldin(const void* p, long i, int f32) {
  return f32 ? ((const float*)p)[i] : b2f(((const u16*)p)[i]);
}
// async global->LDS, 16B per lane; LDS dest = wave-uniform base + lane*16
__device__ __forceinline__ void async16(const void* g, void* l) {
  __builtin_amdgcn_global_load_lds(
      (const __attribute__((address_space(1))) unsigned int*)g,
      (__attribute__((address_space(3))) unsigned int*)l, 16, 0, 0);
}
// Wave-level dtype sniff: all waves scan the SAME 16KB window of x -> identical verdict.
__device__ __forceinline__ int sniff_is_f32(const void* x) {
  const uint4* p = (const uint4*)x;
  const int lane = threadIdx.x & 63;
  unsigned int acc = 0;
  #pragma unroll
  for (int i = 0; i < 16; ++i) {
    uint4 v = p[i * 64 + lane];
    unsigned int w0 = v.x, w1 = v.y, w2 = v.z, w3 = v.w;
    acc |= ((w0 & 0x7F80u) == 0x7F80u) | (((w0 >> 16) & 0x7F80u) == 0x7F80u);
    acc |= ((w1 & 0x7F80u) == 0x7F80u) | (((w1 >> 16) & 0x7F80u) == 0x7F80u);
    acc |= ((w2 & 0x7F80u) == 0x7F80u) | (((w2 >> 16) & 0x7F80u) == 0x7F80u);
    acc |= ((w3 & 0x7F80u) == 0x7F80u) | (((w3 >> 16) & 0x7F80u) == 0x7F80u);
  }
  return __any(acc != 0) ? 1 : 0;
}

// ---------------- k_prep: fused zero-pads + transpose + wA-shuffle + wH/bias pack ----------------
// Roles by block range (independent, disjoint writes):
//   [0,6400): transpose  (b 8 x h 100 x cb 8)
//   [6400,7904): zero xt pad/guard cells (8 x 188)
//   [7904,8928): wA shuffle (1024)
//   [8928,9024): wH + biases (96); block 8928 publishes dtype flag for k_head
__global__ __launch_bounds__(256) void k_prep(const void* __restrict__ x,
                                              const void* __restrict__ w_rpn,
                                              const void* __restrict__ b_rpn,
                                              const void* __restrict__ w_cls,
                                              const void* __restrict__ b_cls,
                                              const void* __restrict__ w_bbox,
                                              const void* __restrict__ b_bbox,
                                              u16* __restrict__ xt,
                                              u16* __restrict__ wA,
                                              u16* __restrict__ wH,
                                              float* __restrict__ bAll,
                                              int* __restrict__ flagOut) {
  const int blk = blockIdx.x;
  const int t = threadIdx.x;
  if (blk < 6400) {
    // ---- transpose: unit = 8 channels x 4 w; reg transpose, 16B stores ----
    const int f32 = sniff_is_f32(x);
    if (t >= 200) return;
    const int b = blk / 800, r = blk - b * 800;
    const int h = r >> 3, cb = r & 7;
    const int co = t / 25, jw = t % 25;
    const int c0 = cb * 64 + co * 8;
    u16 v[8][4];
    if (!f32) {
      const u16* src = (const u16*)x + (long)(b * 512 + c0) * 10000 + h * 100 + jw * 4;
      #pragma unroll
      for (int dc = 0; dc < 8; ++dc) {
        uint2 u = *(const uint2*)(src + (long)dc * 10000);
        const u16* pv = (const u16*)&u;
        v[dc][0] = pv[0]; v[dc][1] = pv[1]; v[dc][2] = pv[2]; v[dc][3] = pv[3];
      }
    } else {
      const float* src = (const float*)x + (long)(b * 512 + c0) * 10000 + h * 100 + jw * 4;
      #pragma unroll
      for (int dc = 0; dc < 8; ++dc) {
        float4 u = *(const float4*)(src + (long)dc * 10000);
        v[dc][0] = f2b(u.x); v[dc][1] = f2b(u.y); v[dc][2] = f2b(u.z); v[dc][3] = f2b(u.w);
      }
    }
    u16* dst = xt + ((long)b * XT_STRIDE + XT_GUARD + (h + 1) * 102 + 1 + jw * 4) * 512 + c0;
    #pragma unroll
    for (int dw = 0; dw < 4; ++dw) {
      union { uint4 u; u16 s[8]; } pk;
      #pragma unroll
      for (int dc = 0; dc < 8; ++dc) pk.s[dc] = v[dc][dw];
      *(uint4*)(dst + (long)dw * 512) = pk.u;
    }
  } else if (blk < 7904) {
    // ---- zero pad/guard cells of xt (48128 uint4 units per batch) ----
    const int i2 = blk - 6400;
    const int b = i2 / 188, bx = i2 - b * 188;
    const int i = bx * 256 + t;
    if (i >= 48128) return;
    int row, sub;
    if (i < 35328) {
      int rr = i >> 6; sub = i & 63;
      row = (rr < 230) ? rr : (10200 + rr);  // [0,230) or [10430,10752)
    } else {
      int j = i - 35328;
      int ci = j >> 6; sub = j & 63;
      int pr = (ci >> 1) + 1;
      row = XT_GUARD + pr * 102 + (ci & 1) * 101;
    }
    uint4 z = {0, 0, 0, 0};
    *(uint4*)(xt + ((long)b * XT_STRIDE + row) * 512 + sub * 8) = z;
  } else if (blk < 8928) {
    // ---- wA: [o][c][3][3] -> [o][cchunk*576 + s*64 + c_in]  (s-fastest K order) ----
    const int f32 = sniff_is_f32(x);
    const int idx = (blk - 7904) * 256 + t;     // o*512+c
    const int o = idx >> 9, c = idx & 511;
    u16* dst = wA + (long)o * 4608 + (c >> 6) * 576 + (c & 63);
    #pragma unroll
    for (int s = 0; s < 9; ++s) dst[s * 64] = f2b(ldin(w_rpn, (long)idx * 9 + s, f32));
  } else {
    // ---- wH [48][512] (45 real + 3 zero rows) + biases + flag publish ----
    const int f32 = sniff_is_f32(x);
    const int idx = (blk - 8928) * 256 + t;     // < 24576
    const int a = idx >> 9, c = idx & 511;
    float v = 0.f;
    if (a < 9) v = ldin(w_cls, a * 512 + c, f32);
    else if (a < 45) v = ldin(w_bbox, (a - 9) * 512 + c, f32);
    wH[idx] = f2b(v);
    if (idx < 512) bAll[idx] = ldin(b_rpn, idx, f32);
    if (c == 0) {
      float bv = 0.f;
      if (a < 9) bv = ldin(b_cls, a, f32);
      else if (a < 45) bv = ldin(b_bbox, a - 9, f32);
      bAll[512 + a] = bv;
    }
    if (blk == 8928 && t == 0) *flagOut = f32;
  }
}

// ---------------- Conv implicit GEMM: 256x256 tile, BK=64, 8-phase counted-vmcnt pipeline ----------------
// T2 (XOR-seg swizzle, pre-swizzled global source, linear LDS) + T3/T4 (8 phases per 2 K-tiles,
// one half-tile staged per phase, s_waitcnt vmcnt(4) ONLY at phases 4 and 8, never 0 in-loop)
// + T5 (setprio around each 16-MFMA cluster). Raw s_barrier everywhere (NO __syncthreads -> no
// vmcnt(0) drain). K-order keeps shift-s fastest so the 9 s-iterations of a c-chunk re-read the
// same xt window back-to-back => B stays L2-resident.
//
// LDS map (u16 idx): [A buf0: 0..16383][B buf0: 16384..32767][A buf1: 32768..49151][B buf1: 49152..65535]
// Tile kt (even) -> buf0, kt+1 -> buf1. Stage lines: 0..3 = A rows ln*64..ln*64+63, 4..7 = B rows.
// Per-phase stage targets a region whose last ds_read was lgkm-waited >=1 barrier earlier:
//   ph1/2: kt+1 B -> buf1-B (freed prev ph6)   ph3/4: kt+2 A -> buf0-A (freed ph2)
//   ph5/6: kt+2 B -> buf0-B (freed ph3-wait)   ph7/8: kt+3 A -> buf1-A (freed ph6)
// vmcnt(4) @ph4-end: kt+1 fully landed, kt+2 A-lines in flight.
// vmcnt(4) @ph8-end: kt+2 fully landed, kt+3 A-lines in flight.
#define BARX() do { asm volatile("" ::: "memory"); __builtin_amdgcn_s_barrier(); asm volatile("" ::: "memory"); } while (0)
#define MF(d, a_, b_) d = __builtin_amdgcn_mfma_f32_16x16x32_bf16(a_, b_, d, 0, 0, 0)

__global__ __launch_bounds__(512, 2) void k_conv(const u16* __restrict__ xt, const u16* __restrict__ wA,
                                                 const float* __restrict__ bAll, u16* __restrict__ feat) {
  __shared__ u16 lds[65536];   // 128 KB
  const int t = threadIdx.x;
  const int i = blockIdx.x;            // 0..655
  const int b = i & 7;                 // batch == XCD: each XCD's L2 caches one batch's xt window
  const int j = i >> 3;                // 0..81
  const int nt = j >> 1, mt = j & 1;   // consecutive j pair mt so concurrent blocks share B-window
  const int m0 = mt * 256, n0 = nt * 256;
  const int lane = t & 63, wv = t >> 6;
  const int wr = wv >> 2, wn = wv & 3;         // 2x4 wave grid; per-wave out = 128 rows x 64 cols
  const int l15 = lane & 15, q = lane >> 4, s7 = l15 & 7;
  const int srow = t >> 3;                     // staging row 0..63 (+64 per line)
  const int sseg = ((t & 7) ^ (srow & 7)) * 8; // XOR-permuted source segment (T2, pre-swizzled src)
  const u16* gA = wA + (long)(m0 + srow) * 4608 + sseg;
  const u16* gB = xt + ((long)b * XT_STRIDE + XT_GUARD + n0 + srow) * 512 + sseg;
  u16* ldsw = lds + wv * 512;                  // wave staging base (1KB/wave per line)
  const int rbA = (wr * 128 + l15) * 64;       // A reader row base (u16 idx in A region)
  const int rbB = 16384 + (wn * 64 + l15) * 64;
  const int sk0 = (q ^ s7) * 8;                // un-swizzled k-seg, ks=0
  const int sk1 = ((4 + q) ^ s7) * 8;          // ks=1

  auto stage = [&](int kt, int ln) {           // ln 0..3 = A lines, 4..7 = B lines
    if (kt >= 72) return;
    const int p = kt & 1;
    const int cchunk = kt / 9, s = kt - cchunk * 9;   // shift s FASTEST
    if (ln < 4) {
      async16(gA + (long)ln * 64 * 4608 + cchunk * 576 + s * 64,
              ldsw + p * 32768 + ln * 4096);
    } else {
      const int off = (s / 3) * 102 + (s - (s / 3) * 3) - 103;  // (dh-1)*102 + (dw-1)
      async16(gB + ((long)(ln - 4) * 64 + off) * 512 + cchunk * 64,
              ldsw + p * 32768 + 16384 + (ln - 4) * 4096);
    }
  };

  f32x4 acc[8][4] = {};
  bf16x8 a0[4][2], a1[4][2], bb[4][2];

  // ---- prologue: tile0 fully + tile1 A-lines; vmcnt(4) => tile0 landed, tile1-A in flight ----
  #pragma unroll
  for (int ln = 0; ln < 8; ++ln) stage(0, ln);
  #pragma unroll
  for (int ln = 0; ln < 4; ++ln) stage(1, ln);
  asm volatile("s_waitcnt vmcnt(4)" ::: "memory");
  __builtin_amdgcn_s_barrier();

  for (int kt = 0; kt < 72; kt += 2) {
    const u16* L0 = lds;           // buf0: tile kt
    const u16* L1 = lds + 32768;   // buf1: tile kt+1
    // ================ ph1: read a0 + bb01 (buf0); stage kt+1 B-lo; MFMA Q(0,0) ================
    #pragma unroll
    for (int mi = 0; mi < 4; ++mi) {
      a0[mi][0] = *(const bf16x8*)(L0 + rbA + mi * 1024 + sk0);
      a0[mi][1] = *(const bf16x8*)(L0 + rbA + mi * 1024 + sk1);
    }
    #pragma unroll
    for (int ni = 0; ni < 2; ++ni) {
      bb[ni][0] = *(const bf16x8*)(L0 + rbB + ni * 1024 + sk0);
      bb[ni][1] = *(const bf16x8*)(L0 + rbB + ni * 1024 + sk1);
    }
    stage(kt + 1, 4); stage(kt + 1, 5);
    BARX();
    __builtin_amdgcn_s_setprio(1);
    #pragma unroll
    for (int mi = 0; mi < 4; ++mi)
      #pragma unroll
      for (int ni = 0; ni < 2; ++ni) { MF(acc[mi][ni], a0[mi][0], bb[ni][0]); MF(acc[mi][ni], a0[mi][1], bb[ni][1]); }
    __builtin_amdgcn_s_setprio(0);
    BARX();
    // ================ ph2: read a1 + bb23 (buf0); stage kt+1 B-hi; MFMA Q(1,0) ================
    #pragma unroll
    for (int mi = 0; mi < 4; ++mi) {
      a1[mi][0] = *(const bf16x8*)(L0 + rbA + (4 + mi) * 1024 + sk0);
      a1[mi][1] = *(const bf16x8*)(L0 + rbA + (4 + mi) * 1024 + sk1);
    }
    #pragma unroll
    for (int ni = 0; ni < 2; ++ni) {
      bb[2 + ni][0] = *(const bf16x8*)(L0 + rbB + (2 + ni) * 1024 + sk0);
      bb[2 + ni][1] = *(const bf16x8*)(L0 + rbB + (2 + ni) * 1024 + sk1);
    }
    stage(kt + 1, 6); stage(kt + 1, 7);
    BARX();
    __builtin_amdgcn_s_setprio(1);
    #pragma unroll
    for (int mi = 0; mi < 4; ++mi)
      #pragma unroll
      for (int ni = 0; ni < 2; ++ni) { MF(acc[4 + mi][ni], a1[mi][0], bb[ni][0]); MF(acc[4 + mi][ni], a1[mi][1], bb[ni][1]); }
    __builtin_amdgcn_s_setprio(0);
    BARX();
    // ================ ph3: stage kt+2 A-lo; MFMA Q(0,1) ================
    stage(kt + 2, 0); stage(kt + 2, 1);
    BARX();
    __builtin_amdgcn_s_setprio(1);
    #pragma unroll
    for (int mi = 0; mi < 4; ++mi)
      #pragma unroll
      for (int ni = 0; ni < 2; ++ni) { MF(acc[mi][2 + ni], a0[mi][0], bb[2 + ni][0]); MF(acc[mi][2 + ni], a0[mi][1], bb[2 + ni][1]); }
    __builtin_amdgcn_s_setprio(0);
    BARX();
    // ================ ph4: stage kt+2 A-hi; MFMA Q(1,1); vmcnt(4) ================
    stage(kt + 2, 2); stage(kt + 2, 3);
    BARX();
    __builtin_amdgcn_s_setprio(1);
    #pragma unroll
    for (int mi = 0; mi < 4; ++mi)
      #pragma unroll
      for (int ni = 0; ni < 2; ++ni) { MF(acc[4 + mi][2 + ni], a1[mi][0], bb[2 + ni][0]); MF(acc[4 + mi][2 + ni], a1[mi][1], bb[2 + ni][1]); }
    __builtin_amdgcn_s_setprio(0);
    if (kt + 2 < 72) { asm volatile("s_waitcnt vmcnt(4)" ::: "memory"); }
    else             { asm volatile("s_waitcnt vmcnt(0)" ::: "memory"); }
    BARX();
    // ================ ph5: read a0 + bb01 (buf1, tile kt+1); stage kt+2 B-lo; Q(0,0) ================
    #pragma unroll
    for (int mi = 0; mi < 4; ++mi) {
      a0[mi][0] = *(const bf16x8*)(L1 + rbA + mi * 1024 + sk0);
      a0[mi][1] = *(const bf16x8*)(L1 + rbA + mi * 1024 + sk1);
    }
    #pragma unroll
    for (int ni = 0; ni < 2; ++ni) {
      bb[ni][0] = *(const bf16x8*)(L1 + rbB + ni * 1024 + sk0);
      bb[ni][1] = *(const bf16x8*)(L1 + rbB + ni * 1024 + sk1);
    }
    stage(kt + 2, 4); stage(kt + 2, 5);
    BARX();
    __builtin_amdgcn_s_setprio(1);
    #pragma unroll
    for (int mi = 0; mi < 4; ++mi)
      #pragma unroll
      for (int ni = 0; ni < 2; ++ni) { MF(acc[mi][ni], a0[mi][0], bb[ni][0]); MF(acc[mi][ni], a0[mi][1], bb[ni][1]); }
    __builtin_amdgcn_s_setprio(0);
    BARX();
    // ================ ph6: read a1 + bb23 (buf1); stage kt+2 B-hi; Q(1,0) ================
    #pragma unroll
    for (int mi = 0; mi < 4; ++mi) {
      a1[mi][0] = *(const bf16x8*)(L1 + rbA + (4 + mi) * 1024 + sk0);
      a1[mi][1] = *(const bf16x8*)(L1 + rbA + (4 + mi) * 1024 + sk1);
    }
    #pragma unroll
    for (int ni = 0; ni < 2; ++ni) {
      bb[2 + ni][0] = *(const bf16x8*)(L1 + rbB + (2 + ni) * 1024 + sk0);
      bb[2 + ni][1] = *(const bf16x8*)(L1 + rbB + (2 + ni) * 1024 + sk1);
    }
    stage(kt + 2, 6); stage(kt + 2, 7);
    BARX();
    __builtin_amdgcn_s_setprio(1);
    #pragma unroll
    for (int mi = 0; mi < 4; ++mi)
      #pragma unroll
      for (int ni = 0; ni < 2; ++ni) { MF(acc[4 + mi][ni], a1[mi][0], bb[ni][0]); MF(acc[4 + mi][ni], a1[mi][1], bb[ni][1]); }
    __builtin_amdgcn_s_setprio(0);
    BARX();
    // ================ ph7: stage kt+3 A-lo; Q(0,1) ================
    stage(kt + 3, 0); stage(kt + 3, 1);
    BARX();
    __builtin_amdgcn_s_setprio(1);
    #pragma unroll
    for (int mi = 0; mi < 4; ++mi)
      #pragma unroll
      for (int ni = 0; ni < 2; ++ni) { MF(acc[mi][2 + ni], a0[mi][0], bb[2 + ni][0]); MF(acc[mi][2 + ni], a0[mi][1], bb[2 + ni][1]); }
    __builtin_amdgcn_s_setprio(0);
    BARX();
    // ================ ph8: stage kt+3 A-hi; Q(1,1); vmcnt(4) ================
    stage(kt + 3, 2); stage(kt + 3, 3);
    BARX();
    __builtin_amdgcn_s_setprio(1);
    #pragma unroll
    for (int mi = 0; mi < 4; ++mi)
      #pragma unroll
      for (int ni = 0; ni < 2; ++ni) { MF(acc[4 + mi][2 + ni], a1[mi][0], bb[2 + ni][0]); MF(acc[4 + mi][2 + ni], a1[mi][1], bb[2 + ni][1]); }
    __builtin_amdgcn_s_setprio(0);
    if (kt + 3 < 72) { asm volatile("s_waitcnt vmcnt(4)" ::: "memory"); }
    else             { asm volatile("s_waitcnt vmcnt(0)" ::: "memory"); }
    BARX();
  }

  // ---- epilogue: bias + ReLU + bf16 pack, 8B stores ----
  u16* fb = feat + (long)b * NPAD * 512;
  #pragma unroll
  for (int mi = 0; mi < 8; ++mi) {
    const int ol = wr * 128 + mi * 16 + q * 4;
    const float4 bv = *(const float4*)(bAll + m0 + ol);
    const float bvr[4] = {bv.x, bv.y, bv.z, bv.w};
    #pragma unroll
    for (int ni = 0; ni < 4; ++ni) {
      const int p = n0 + wn * 64 + ni * 16 + l15;
      unsigned long long pk = 0;
      #pragma unroll
      for (int r = 0; r < 4; ++r) {
        float v = acc[mi][ni][r] + bvr[r];
        v = v > 0.f ? v : 0.f;
        pk |= ((unsigned long long)f2b(v)) << (16 * r);
      }
      *(unsigned long long*)(fb + (long)p * 512 + m0 + ol) = pk;
    }
  }
}

// ---------------- k_head: LDS-free MFMA, dual-dtype store (flag from ws) ----------------
__global__ __launch_bounds__(256) void k_head(const u16* __restrict__ feat, const u16* __restrict__ wH,
                                              const float* __restrict__ bAll, void* __restrict__ out,
                                              const int* __restrict__ flag) {
  const int f32 = *flag;
  const int t = threadIdx.x;
  const int lane = t & 63, wv = t >> 6;
  const int l15 = lane & 15, q = lane >> 4;
  const int slot = blockIdx.x * 64 + wv * 16;          // 64 p-slots per block; NPAD%64==0
  const int b = slot / NPAD, p0 = slot - b * NPAD;
  const u16* fp = feat + ((long)b * NPAD + p0 + l15) * 512 + q * 8;
  const u16* ap = wH + (long)l15 * 512 + q * 8;
  f32x4 acc[3] = {};
  #pragma unroll
  for (int ks = 0; ks < 16; ++ks) {
    const int k0 = ks * 32;
    bf16x8 bf = *(const bf16x8*)(fp + k0);
    bf16x8 a0 = *(const bf16x8*)(ap + k0);
    bf16x8 a1 = *(const bf16x8*)(ap + 16 * 512 + k0);
    bf16x8 a2 = *(const bf16x8*)(ap + 32 * 512 + k0);
    acc[0] = __builtin_amdgcn_mfma_f32_16x16x32_bf16(a0, bf, acc[0], 0, 0, 0);
    acc[1] = __builtin_amdgcn_mfma_f32_16x16x32_bf16(a1, bf, acc[1], 0, 0, 0);
    acc[2] = __builtin_amdgcn_mfma_f32_16x16x32_bf16(a2, bf, acc[2], 0, 0, 0);
  }
  const int p = p0 + l15;
  const int pr = p / 102, pc = p - pr * 102;
  if (pr < 1 || pr > 100 || pc < 1 || pc > 100) return;  // pad position
  const int h = pr - 1, w = pc - 1;
  #pragma unroll
  for (int mi = 0; mi < 3; ++mi) {
    #pragma unroll
    for (int r = 0; r < 4; ++r) {
      const int a = mi * 16 + q * 4 + r;
      if (a >= 45) continue;
      float v = acc[mi][r] + bAll[512 + a];
      long oidx;
      if (a < 9) oidx = ((long)(b * 9 + a)) * 10000 + h * 100 + w;
      else       oidx = 720000 + ((long)(b * 36 + (a - 9))) * 10000 + h * 100 + w;
      if (f32) ((float*)out)[oidx] = v;
      else     ((u16*)out)[oidx] = f2b(v);
    }
  }
}

extern "C" void kernel_launch(void* const* d_in, const int* in_sizes, int n_in,
                              void* d_out, int out_size, void* d_ws, size_t ws_size,
                              hipStream_t stream) {
  const void* x      = d_in[0];
  const void* w_rpn  = d_in[1];
  const void* b_rpn  = d_in[2];
  const void* w_cls  = d_in[3];
  const void* b_cls  = d_in[4];
  const void* w_bbox = d_in[5];
  const void* b_bbox = d_in[6];
  char* ws = (char*)d_ws;
  u16*  xt   = (u16*) (ws);                 // 8*10752*512*2 = 88,080,384
  u16*  feat = (u16*) (ws + 88080384);      // 8*10496*512*2 = 85,983,232
  u16*  wA   = (u16*) (ws + 174063616);     // 512*4608*2    =  4,718,592
  u16*  wH   = (u16*) (ws + 178782208);     // 48*512*2      =     49,152
  float* bAll= (float*)(ws + 178831360);    // 560*4
  int*  flag = (int*) (ws + 178833600);     // 4

  k_prep<<<9024, 256, 0, stream>>>(x, w_rpn, b_rpn, w_cls, b_cls, w_bbox, b_bbox,
                                   xt, wA, wH, bAll, flag);
  k_conv<<<656, 512, 0, stream>>>(xt, wA, bAll, feat);
  k_head<<<1312, 256, 0, stream>>>(feat, wH, bAll, d_out, flag);
}